// Round 20
// baseline (115.866 us; speedup 1.0000x reference)
//
#include <hip/hip_runtime.h>
#include <hip/hip_bf16.h>

// Sizes: S=128, B=64, N=64, K=16, P=48, M=32
// Outputs: A [S,B,64,64] (C=4096), Bo [S,B,64,32] (C=2048), Cc [S,B,48,64] (C=3072)
#define SB 8192   // S*B

typedef float f4 __attribute__((ext_vector_type(4)));  // clang-native vec4

__device__ __forceinline__ float fsig(float x) {
    return __builtin_amdgcn_rcpf(1.f + __expf(-x));
}
__device__ __forceinline__ float ftanh(float x) {
    // tanh(x) = 1 - 2/(exp(2x)+1); correct limits at +-inf via rcp(inf)=0
    return fmaf(-2.f, __builtin_amdgcn_rcpf(1.f + __expf(2.f * x)), 1.f);
}

// ---------------------------------------------------------------------------
// Kernel 1 (R19-exact): xg[row][t*4+q] = dot(x[row], W_ih[q*16+t]) + b.
// Gate-interleaved so the scan loads one float4 per (step, batch, unit).
// ---------------------------------------------------------------------------
__global__ __launch_bounds__(256) void xgate_kernel(
    const float* __restrict__ x,    // [8192][64]
    const float* __restrict__ Wih,  // [64][64]
    const float* __restrict__ bih,
    const float* __restrict__ bhh,
    float* __restrict__ xg)         // [8192][16][4] gate-interleaved
{
    __shared__ float xs[4][64];
    const int tid = threadIdx.x;
    const int rl  = tid >> 6;
    const int g   = tid & 63;           // weight row: g = q*16 + t
    const size_t rowBase = (size_t)blockIdx.x * 4;

    xs[rl][g] = x[rowBase * 64 + tid];
    __syncthreads();

    const float* xr = xs[rl];
    float acc = bih[g] + bhh[g];
#pragma unroll
    for (int n = 0; n < 64; n += 4) {
        f4 wv = *reinterpret_cast<const f4*>(&Wih[g * 64 + n]);
        acc = fmaf(xr[n + 0], wv.x, acc);
        acc = fmaf(xr[n + 1], wv.y, acc);
        acc = fmaf(xr[n + 2], wv.z, acc);
        acc = fmaf(xr[n + 3], wv.w, acc);
    }
    xg[(rowBase + rl) * 64 + (g & 15) * 4 + (g >> 4)] = acc;
}

// ---------------------------------------------------------------------------
// Kernel 2 (R19-exact): barrier-free single-wave LSTM scan. 16 blocks x 64.
// Same-wave DS FIFO => h publish/read needs only a compiler fence; no
// vmcnt/lgkmcnt(0) drains on the serial chain; 4-deep xg prefetch.
// ---------------------------------------------------------------------------
__global__ __launch_bounds__(64) void lstm_scan_kernel(
    const float* __restrict__ xg,   // [S][B][16][4]
    const float* __restrict__ Whh,  // [64][16]
    float* __restrict__ w)          // [S][B][16]
{
    __shared__ alignas(16) float hs[64];
    const int tid = threadIdx.x;
    const int t  = tid & 15;        // hidden unit
    const int b4 = tid >> 4;        // local batch (0..3)
    const int b  = blockIdx.x * 4 + b4;

    float wi[16], wf[16], wg[16], wo[16];
#pragma unroll
    for (int k = 0; k < 16; ++k) {
        wi[k] = Whh[(0 * 16 + t) * 16 + k];
        wf[k] = Whh[(1 * 16 + t) * 16 + k];
        wg[k] = Whh[(2 * 16 + t) * 16 + k];
        wo[k] = Whh[(3 * 16 + t) * 16 + k];
    }

    // f4 view: element (s,b,t) at f4-index (s*64+b)*16 + t; s-stride = 1024
    const f4* xp = reinterpret_cast<const f4*>(xg) + b * 16 + t;

    // 4-deep register prefetch (statically indexed via unroll)
    f4 pf[4];
#pragma unroll
    for (int i = 0; i < 4; ++i) pf[i] = xp[(size_t)i * 1024];

    float h = 0.f, c = 0.f;
    for (int s = 0; s < 128; s += 4) {
#pragma unroll
        for (int u = 0; u < 4; ++u) {
            f4 xv = pf[u];
            const int nidx = (s + u + 4 < 128) ? (s + u + 4) : 127;
            pf[u] = xp[(size_t)nidx * 1024];     // refill 4 ahead (discardable tail)

            // publish h[b][t]; same-wave DS FIFO => reads below see it.
            hs[tid] = h;
            asm volatile("" ::: "memory");       // compiler fence only (no waitcnt)
            union { f4 v[4]; float f[16]; } hh;
            hh.v[0] = *reinterpret_cast<const f4*>(&hs[b4 * 16 + 0]);
            hh.v[1] = *reinterpret_cast<const f4*>(&hs[b4 * 16 + 4]);
            hh.v[2] = *reinterpret_cast<const f4*>(&hs[b4 * 16 + 8]);
            hh.v[3] = *reinterpret_cast<const f4*>(&hs[b4 * 16 + 12]);

            float ai = xv.x, af = xv.y, ag = xv.z, ao = xv.w;
#pragma unroll
            for (int k = 0; k < 16; ++k) {
                float hk = hh.f[k];
                ai = fmaf(hk, wi[k], ai);
                af = fmaf(hk, wf[k], af);
                ag = fmaf(hk, wg[k], ag);
                ao = fmaf(hk, wo[k], ao);
            }
            float ig = fsig(ai), fg = fsig(af), og = fsig(ao);
            float gt = ftanh(ag);
            c = fg * c + ig * gt;
            h = og * ftanh(c);
            w[((size_t)(s + u) * 64 + b) * 16 + t] = h;   // fire-and-forget
        }
    }
}

// ---------------------------------------------------------------------------
// Kernel 3: out[row][i] = sum_k w[row][k]*M[k][i].
// SINGLE CHANGE vs R19: nontemporal f4 stores — the 302 MB write-once stream
// bypasses L2, keeping the As/Bs/Cs working set and w L2-resident instead of
// being continuously evicted by write-allocate.
// ---------------------------------------------------------------------------
__global__ __launch_bounds__(256) void wsum_all_kernel(
    const float* __restrict__ w,   // [8192][16]
    const float* __restrict__ As, const float* __restrict__ Bs,
    const float* __restrict__ Cs,
    float* __restrict__ outA, float* __restrict__ outB, float* __restrict__ outC)
{
    const int tid = threadIdx.x;
    const int bid = blockIdx.x;

    const float* M; float* o; int C, local, colTiles;
    if (bid < 1024)      { M = As; o = outA; C = 4096; local = bid;        colTiles = 4; }
    else if (bid < 1536) { M = Bs; o = outB; C = 2048; local = bid - 1024; colTiles = 2; }
    else                 { M = Cs; o = outC; C = 3072; local = bid - 1536; colTiles = 3; }

    const int colTile  = local % colTiles;
    const int rowStart = (local / colTiles) * 32;
    const int i4 = colTile * 1024 + tid * 4;

    f4 m[16];
#pragma unroll
    for (int k = 0; k < 16; ++k)
        m[k] = *reinterpret_cast<const f4*>(&M[(size_t)k * C + i4]);

    const float* wp = w + (size_t)rowStart * 16;   // wave-uniform
    float* op = o + (size_t)rowStart * C + i4;

#pragma unroll 2
    for (int r = 0; r < 32; ++r) {
        f4 acc = (f4)0.f;
#pragma unroll
        for (int k = 0; k < 16; ++k)
            acc += wp[r * 16 + k] * m[k];          // uniform -> s_load
        __builtin_nontemporal_store(acc, reinterpret_cast<f4*>(op));
        op += C;
    }
}

// ---------------------------------------------------------------------------
extern "C" void kernel_launch(void* const* d_in, const int* in_sizes, int n_in,
                              void* d_out, int out_size, void* d_ws, size_t ws_size,
                              hipStream_t stream) {
    const float* state = (const float*)d_in[0];
    const float* W_ih  = (const float*)d_in[1];
    const float* W_hh  = (const float*)d_in[2];
    const float* b_ih  = (const float*)d_in[3];
    const float* b_hh  = (const float*)d_in[4];
    const float* As    = (const float*)d_in[5];
    const float* Bs    = (const float*)d_in[6];
    const float* Cs    = (const float*)d_in[7];
    float* out = (float*)d_out;

    float* xg = (float*)d_ws;            // 8192*64 floats
    float* w  = xg + (size_t)SB * 64;    // 8192*16 floats

    xgate_kernel<<<SB / 4, 256, 0, stream>>>(state, W_ih, b_ih, b_hh, xg);
    lstm_scan_kernel<<<16, 64, 0, stream>>>(xg, W_hh, w);

    float* outA = out;
    float* outB = out + (size_t)SB * 4096;
    float* outC = out + (size_t)SB * 4096 + (size_t)SB * 2048;

    wsum_all_kernel<<<2304, 256, 0, stream>>>(w, As, Bs, Cs, outA, outB, outC);
}

// Round 21
// 104.938 us; speedup vs baseline: 1.1041x; 1.1041x over previous
//
#include <hip/hip_runtime.h>
#include <hip/hip_bf16.h>

// Sizes: S=128, B=64, N=64, K=16, P=48, M=32
// Outputs: A [S,B,64,64] (C=4096), Bo [S,B,64,32] (C=2048), Cc [S,B,48,64] (C=3072)
#define SB 8192   // S*B

typedef float f4 __attribute__((ext_vector_type(4)));  // clang-native vec4

__device__ __forceinline__ float fsig(float x) {
    return __builtin_amdgcn_rcpf(1.f + __expf(-x));
}
__device__ __forceinline__ float ftanh(float x) {
    // tanh(x) = 1 - 2/(exp(2x)+1); correct limits at +-inf via rcp(inf)=0
    return fmaf(-2.f, __builtin_amdgcn_rcpf(1.f + __expf(2.f * x)), 1.f);
}

// ---------------------------------------------------------------------------
// Kernel 1 (R19-exact): xg[row][t*4+q] = dot(x[row], W_ih[q*16+t]) + b.
// Gate-interleaved so the scan loads one float4 per (step, batch, unit).
// ---------------------------------------------------------------------------
__global__ __launch_bounds__(256) void xgate_kernel(
    const float* __restrict__ x,    // [8192][64]
    const float* __restrict__ Wih,  // [64][64]
    const float* __restrict__ bih,
    const float* __restrict__ bhh,
    float* __restrict__ xg)         // [8192][16][4] gate-interleaved
{
    __shared__ float xs[4][64];
    const int tid = threadIdx.x;
    const int rl  = tid >> 6;
    const int g   = tid & 63;           // weight row: g = q*16 + t
    const size_t rowBase = (size_t)blockIdx.x * 4;

    xs[rl][g] = x[rowBase * 64 + tid];
    __syncthreads();

    const float* xr = xs[rl];
    float acc = bih[g] + bhh[g];
#pragma unroll
    for (int n = 0; n < 64; n += 4) {
        f4 wv = *reinterpret_cast<const f4*>(&Wih[g * 64 + n]);
        acc = fmaf(xr[n + 0], wv.x, acc);
        acc = fmaf(xr[n + 1], wv.y, acc);
        acc = fmaf(xr[n + 2], wv.z, acc);
        acc = fmaf(xr[n + 3], wv.w, acc);
    }
    xg[(rowBase + rl) * 64 + (g & 15) * 4 + (g >> 4)] = acc;
}

// ---------------------------------------------------------------------------
// Kernel 2 (R19-exact): barrier-free single-wave LSTM scan. 16 blocks x 64.
// Same-wave DS FIFO => h publish/read needs only a compiler fence; no
// vmcnt/lgkmcnt(0) drains on the serial chain; 4-deep xg prefetch.
// ---------------------------------------------------------------------------
__global__ __launch_bounds__(64) void lstm_scan_kernel(
    const float* __restrict__ xg,   // [S][B][16][4]
    const float* __restrict__ Whh,  // [64][16]
    float* __restrict__ w)          // [S][B][16]
{
    __shared__ alignas(16) float hs[64];
    const int tid = threadIdx.x;
    const int t  = tid & 15;        // hidden unit
    const int b4 = tid >> 4;        // local batch (0..3)
    const int b  = blockIdx.x * 4 + b4;

    float wi[16], wf[16], wg[16], wo[16];
#pragma unroll
    for (int k = 0; k < 16; ++k) {
        wi[k] = Whh[(0 * 16 + t) * 16 + k];
        wf[k] = Whh[(1 * 16 + t) * 16 + k];
        wg[k] = Whh[(2 * 16 + t) * 16 + k];
        wo[k] = Whh[(3 * 16 + t) * 16 + k];
    }

    // f4 view: element (s,b,t) at f4-index (s*64+b)*16 + t; s-stride = 1024
    const f4* xp = reinterpret_cast<const f4*>(xg) + b * 16 + t;

    // 4-deep register prefetch (statically indexed via unroll)
    f4 pf[4];
#pragma unroll
    for (int i = 0; i < 4; ++i) pf[i] = xp[(size_t)i * 1024];

    float h = 0.f, c = 0.f;
    for (int s = 0; s < 128; s += 4) {
#pragma unroll
        for (int u = 0; u < 4; ++u) {
            f4 xv = pf[u];
            const int nidx = (s + u + 4 < 128) ? (s + u + 4) : 127;
            pf[u] = xp[(size_t)nidx * 1024];     // refill 4 ahead (discardable tail)

            // publish h[b][t]; same-wave DS FIFO => reads below see it.
            hs[tid] = h;
            asm volatile("" ::: "memory");       // compiler fence only (no waitcnt)
            union { f4 v[4]; float f[16]; } hh;
            hh.v[0] = *reinterpret_cast<const f4*>(&hs[b4 * 16 + 0]);
            hh.v[1] = *reinterpret_cast<const f4*>(&hs[b4 * 16 + 4]);
            hh.v[2] = *reinterpret_cast<const f4*>(&hs[b4 * 16 + 8]);
            hh.v[3] = *reinterpret_cast<const f4*>(&hs[b4 * 16 + 12]);

            float ai = xv.x, af = xv.y, ag = xv.z, ao = xv.w;
#pragma unroll
            for (int k = 0; k < 16; ++k) {
                float hk = hh.f[k];
                ai = fmaf(hk, wi[k], ai);
                af = fmaf(hk, wf[k], af);
                ag = fmaf(hk, wg[k], ag);
                ao = fmaf(hk, wo[k], ao);
            }
            float ig = fsig(ai), fg = fsig(af), og = fsig(ao);
            float gt = ftanh(ag);
            c = fg * c + ig * gt;
            h = og * ftanh(c);
            w[((size_t)(s + u) * 64 + b) * 16 + t] = h;   // fire-and-forget
        }
    }
}

// ---------------------------------------------------------------------------
// Kernel 3 (R19-exact): out[row][i] = sum_k w[row][k]*M[k][i].
// 2304 blocks = 9/CU; wave-uniform w -> scalar s_load; m[16] in registers;
// PLAIN coalesced f4 stores (R20 A/B: nontemporal was +10.7 us — L2 write
// aggregation on plain stores wins for this stream).
// ---------------------------------------------------------------------------
__global__ __launch_bounds__(256) void wsum_all_kernel(
    const float* __restrict__ w,   // [8192][16]
    const float* __restrict__ As, const float* __restrict__ Bs,
    const float* __restrict__ Cs,
    float* __restrict__ outA, float* __restrict__ outB, float* __restrict__ outC)
{
    const int tid = threadIdx.x;
    const int bid = blockIdx.x;

    const float* M; float* o; int C, local, colTiles;
    if (bid < 1024)      { M = As; o = outA; C = 4096; local = bid;        colTiles = 4; }
    else if (bid < 1536) { M = Bs; o = outB; C = 2048; local = bid - 1024; colTiles = 2; }
    else                 { M = Cs; o = outC; C = 3072; local = bid - 1536; colTiles = 3; }

    const int colTile  = local % colTiles;
    const int rowStart = (local / colTiles) * 32;
    const int i4 = colTile * 1024 + tid * 4;

    f4 m[16];
#pragma unroll
    for (int k = 0; k < 16; ++k)
        m[k] = *reinterpret_cast<const f4*>(&M[(size_t)k * C + i4]);

    const float* wp = w + (size_t)rowStart * 16;   // wave-uniform
    float* op = o + (size_t)rowStart * C + i4;

#pragma unroll 2
    for (int r = 0; r < 32; ++r) {
        f4 acc = (f4)0.f;
#pragma unroll
        for (int k = 0; k < 16; ++k)
            acc += wp[r * 16 + k] * m[k];          // uniform -> s_load
        *reinterpret_cast<f4*>(op) = acc;
        op += C;
    }
}

// ---------------------------------------------------------------------------
extern "C" void kernel_launch(void* const* d_in, const int* in_sizes, int n_in,
                              void* d_out, int out_size, void* d_ws, size_t ws_size,
                              hipStream_t stream) {
    const float* state = (const float*)d_in[0];
    const float* W_ih  = (const float*)d_in[1];
    const float* W_hh  = (const float*)d_in[2];
    const float* b_ih  = (const float*)d_in[3];
    const float* b_hh  = (const float*)d_in[4];
    const float* As    = (const float*)d_in[5];
    const float* Bs    = (const float*)d_in[6];
    const float* Cs    = (const float*)d_in[7];
    float* out = (float*)d_out;

    float* xg = (float*)d_ws;            // 8192*64 floats
    float* w  = xg + (size_t)SB * 64;    // 8192*16 floats

    xgate_kernel<<<SB / 4, 256, 0, stream>>>(state, W_ih, b_ih, b_hh, xg);
    lstm_scan_kernel<<<16, 64, 0, stream>>>(xg, W_hh, w);

    float* outA = out;
    float* outB = out + (size_t)SB * 4096;
    float* outC = out + (size_t)SB * 4096 + (size_t)SB * 2048;

    wsum_all_kernel<<<2304, 256, 0, stream>>>(w, As, Bs, Cs, outA, outB, outC);
}